// Round 8
// baseline (920.432 us; speedup 1.0000x reference)
//
#include <hip/hip_runtime.h>
#include <cstddef>

#define THRESH 1e-6f
#define SPIN_LIMIT (1 << 20)

__device__ __forceinline__ float thrf(float x) { return x > THRESH ? x : 0.0f; }
__device__ __forceinline__ float sigm(float x) { return 1.0f / (1.0f + expf(-x)); }
__device__ __forceinline__ void macc4(float4& a, float4 w, float4 h) {
    a.x += w.x * h.x; a.y += w.y * h.y; a.z += w.z * h.z; a.w += w.w * h.w;
}
__device__ __forceinline__ float hsum4(float4 a) { return a.x + a.y + a.z + a.w; }

// ---------------------------------------------------------------------------
// K1: fused gather+MLP GEMM (unchanged — proven).
// ---------------------------------------------------------------------------
__global__ __launch_bounds__(256) void k_embed_gemm(const int* __restrict__ tok,
                                                    const float* __restrict__ W1,
                                                    const float* __restrict__ b1,
                                                    const float* __restrict__ W2,
                                                    const float* __restrict__ b2,
                                                    float* __restrict__ emb) {
    constexpr int BM = 64, BN = 64, BK = 32, K = 512, N = 256;
    __shared__ float As[BK][BM + 1];
    __shared__ float Bs[BK][BN];

    const int tid = threadIdx.x;
    const int bm = blockIdx.x * BM;
    const int bn = blockIdx.y * BN;
    const int tn = (tid & 15) * 4;
    const int tm = (tid >> 4) * 4;

    float acc[4][4] = {};

    for (int k0 = 0; k0 < K; k0 += BK) {
        for (int i = tid; i < BM * BK / 4; i += 256) {
            int c4 = (i & (BK / 4 - 1)) * 4;
            int r  = i / (BK / 4);
            int tv = tok[bm + r];
            float4 v  = *(const float4*)(W1 + (size_t)tv * K + k0 + c4);
            float4 bb = *(const float4*)(b1 + k0 + c4);
            As[c4 + 0][r] = thrf(v.x + bb.x);
            As[c4 + 1][r] = thrf(v.y + bb.y);
            As[c4 + 2][r] = thrf(v.z + bb.z);
            As[c4 + 3][r] = thrf(v.w + bb.w);
        }
        for (int i = tid; i < BK * BN / 4; i += 256) {
            int n4 = (i & 15) * 4;
            int kk = i >> 4;
            *(float4*)&Bs[kk][n4] = *(const float4*)(W2 + (size_t)(k0 + kk) * N + bn + n4);
        }
        __syncthreads();

        for (int k = 0; k < BK; ++k) {
            float a0 = As[k][tm + 0], a1 = As[k][tm + 1];
            float a2 = As[k][tm + 2], a3 = As[k][tm + 3];
            float b0 = Bs[k][tn + 0], b1v = Bs[k][tn + 1];
            float b2v = Bs[k][tn + 2], b3v = Bs[k][tn + 3];
            acc[0][0] += a0 * b0;  acc[0][1] += a0 * b1v;
            acc[0][2] += a0 * b2v; acc[0][3] += a0 * b3v;
            acc[1][0] += a1 * b0;  acc[1][1] += a1 * b1v;
            acc[1][2] += a1 * b2v; acc[1][3] += a1 * b3v;
            acc[2][0] += a2 * b0;  acc[2][1] += a2 * b1v;
            acc[2][2] += a2 * b2v; acc[2][3] += a2 * b3v;
            acc[3][0] += a3 * b0;  acc[3][1] += a3 * b1v;
            acc[3][2] += a3 * b2v; acc[3][3] += a3 * b3v;
        }
        __syncthreads();
    }

    const float4 bv = *(const float4*)(b2 + bn + tn);
    for (int i = 0; i < 4; ++i) {
        int m = bm + tm + i;
        float4 o;
        o.x = thrf(acc[i][0] + bv.x);
        o.y = thrf(acc[i][1] + bv.y);
        o.z = thrf(acc[i][2] + bv.z);
        o.w = thrf(acc[i][3] + bv.w);
        *(float4*)(emb + (size_t)m * N + bn + tn) = o;
    }
}

// ---------------------------------------------------------------------------
// K2: GRU scan — R4's proven structure (507us, 228 VGPR) VERBATIM on the
// critical path, + fused x-projection (k_xproj kernel DELETED).
//
// 256 blocks x 256 threads = 8 groups (bid&7) x 32 members (bid>>3).
// Member owns j-slice [m*16,m*16+16); group owns batches [g*4,g*4+4).
// jl = tid&15 (j), kc = tid>>4 (k-chunk, strided k = kc*4 + i*64).
// W_hh rows in VGPRs (96 f/thread — R4's mapping, the one regalloc keeps;
// R5/R6/R7 all lost this).  h-dot reads are 16-way LDS broadcast (4 unique
// addrs/instr -> near-free).  LL flag-in-data exchange, red[]-reduce,
// 64-lane finalize: all R4 verbatim.
//
// FUSED X-PROJECTION (new): x(t)[g][j][b] = W_ih[g*512+j]·emb[t*32+b] + b_ih.
//   - Wx[48][260] LDS (48KB, staged once; stride 260 -> 2-way/broadcast free)
//   - emb rows double-buffered in el[2][4][260]; global prefetch issued at
//     step top (regs), written to LDS after the 1st barrier.
//   - wave 0 computes x(t+1) at END of step t, right after publish — inside
//     the ~1.5us LL-poll shadow (other waves are polling; the barrier waits
//     for the slowest remote publisher anyway).  768 v_fma + 256 broadcast
//     b128 ~ 0.6us.  Results in xl[2][3][64]; finalize reads 3 LDS floats
//     instead of 3 global xp loads.
//   - races: el write (post-barrier, parity (t+1)&1) vs x-dot read (same
//     parity, after 2nd barrier) ordered; next overwrite of that parity is
//     at step t+2 post-barrier, gated behind wave 0's traversal of t+1.
//     xl produced and consumed by wave 0 only (program order).
// ---------------------------------------------------------------------------
__global__ __launch_bounds__(256) void k_scan(const float* __restrict__ emb,   // (4096,256)
                                              const float* __restrict__ W_hh,  // (1536,512)
                                              const float* __restrict__ W_ih,  // (1536,256)
                                              const float* __restrict__ b_hh,  // (1536)
                                              const float* __restrict__ b_ih,  // (1536)
                                              unsigned long long* __restrict__ hx, // (2,32,512) u64
                                              float* __restrict__ h_out) {     // (32,512)
    constexpr int HS = 520;                        // pad: conflict-free h reads
    __shared__ __align__(16) float hl[4][HS];      //  8320 B  h staging
    __shared__ float red[4][16][12];               //  3072 B  cross-wave reduce
    __shared__ __align__(16) float Wx[48][260];    // 49920 B  W_ih rows
    __shared__ __align__(16) float el[2][4][260];  //  8320 B  emb row dbuf
    __shared__ float xl[2][3][64];                 //  1536 B  x results

    const int tid = threadIdx.x;
    const int g   = blockIdx.x & 7;
    const int m   = blockIdx.x >> 3;
    const int jl  = tid & 15;
    const int kc  = tid >> 4;                      // 0..15
    const int jglob = m * 16 + jl;

    // ---- W_hh rows -> registers (R4 verbatim; constant across 128 steps) --
    float4 wr[8], wz[8], wn[8];
#pragma unroll
    for (int i = 0; i < 8; ++i) {
        const int k = kc * 4 + i * 64;
        wr[i] = *(const float4*)(W_hh + (size_t)jglob * 512 + k);
        wz[i] = *(const float4*)(W_hh + (size_t)(512 + jglob) * 512 + k);
        wn[i] = *(const float4*)(W_hh + (size_t)(1024 + jglob) * 512 + k);
    }

    // ---- stage member's 48 W_ih rows -> LDS (once) ----
    for (int idx = tid; idx < 48 * 64; idx += 256) {
        const int rr = idx >> 6, c4 = (idx & 63) * 4;
        const int row = (rr >> 4) * 512 + m * 16 + (rr & 15);
        *(float4*)&Wx[rr][c4] = *(const float4*)(W_ih + (size_t)row * 256 + c4);
    }
    // ---- stage emb rows for t=0 ----
    {
        const int rr = tid >> 6, c4 = (tid & 63) * 4;
        *(float4*)&el[0][rr][c4] = *(const float4*)(emb + (size_t)(g * 4 + rr) * 256 + c4);
    }

    // finalizer persistent state (tid < 64): (jf, bf) -> one h element
    const int jf  = tid & 15;
    const int bf  = (tid >> 4) & 3;
    const int jfg = m * 16 + jf;
    const int bg  = g * 4 + bf;
    float bhr = 0.f, bhz = 0.f, bhn = 0.f, hprev = 0.f;
    float bxr = 0.f, bxz = 0.f, bxn = 0.f;
    if (tid < 64) {
        bhr = b_hh[jfg];        bhz = b_hh[512 + jfg];  bhn = b_hh[1024 + jfg];
        bxr = b_ih[jfg];        bxz = b_ih[512 + jfg];  bxn = b_ih[1024 + jfg];
    }

    // h(0) = 0
    for (int i = tid; i < 4 * HS; i += 256) ((float*)hl)[i] = 0.f;
    __syncthreads();   // orders Wx/el[0]/hl staging

    // ---- x(0) by wave 0 (consumed by wave 0 at t=0 finalize: prog order) --
    if (tid < 64) {
        float4 a0 = make_float4(0,0,0,0), a1 = a0, a2 = a0;
#pragma unroll 8
        for (int i = 0; i < 64; ++i) {
            const float4 e = *(const float4*)&el[0][bf][i * 4];
            macc4(a0, *(const float4*)&Wx[jf][i * 4],       e);
            macc4(a1, *(const float4*)&Wx[16 + jf][i * 4],  e);
            macc4(a2, *(const float4*)&Wx[32 + jf][i * 4],  e);
        }
        xl[0][0][bf * 16 + jf] = hsum4(a0) + bxr;
        xl[0][1][bf * 16 + jf] = hsum4(a1) + bxz;
        xl[0][2][bf * 16 + jf] = hsum4(a2) + bxn;
    }

    for (int t = 0; t < 128; ++t) {
        // emb prefetch for rows (t+1): issue global loads into regs now
        const int err = tid >> 6, ec4 = (tid & 63) * 4;
        float4 epf = make_float4(0.f, 0.f, 0.f, 0.f);
        if (t < 127)
            epf = *(const float4*)(emb + (size_t)((t + 1) * 32 + g * 4 + err) * 256 + ec4);

        // ---- LL receive of h(t) (t>0): R4 verbatim ----
        if (t > 0) {
            const unsigned tag = (unsigned)t;
            unsigned long long* base = hx + (size_t)(t & 1) * 16384 + (size_t)(g * 4) * 512;
            unsigned long long v[8];
#pragma unroll
            for (int p = 0; p < 8; ++p)
                v[p] = __hip_atomic_load(base + tid + 256 * p,
                                         __ATOMIC_RELAXED, __HIP_MEMORY_SCOPE_AGENT);
            int spins = 0;
            for (;;) {
                bool all = true;
#pragma unroll
                for (int p = 0; p < 8; ++p) {
                    if ((unsigned)(v[p] >> 32) != tag) {
                        all = false;
                        v[p] = __hip_atomic_load(base + tid + 256 * p,
                                                 __ATOMIC_RELAXED, __HIP_MEMORY_SCOPE_AGENT);
                    }
                }
                if (all || ++spins > SPIN_LIMIT) break;
                __builtin_amdgcn_s_sleep(1);
            }
#pragma unroll
            for (int p = 0; p < 8; ++p) {
                const int flat = tid + 256 * p;
                union { unsigned u; float f; } cv;
                cv.u = (unsigned)v[p];
                hl[flat >> 9][flat & 511] = cv.f;
            }
        }
        __syncthreads();   // barrier 1 (stage complete)

        // write emb prefetch to the other parity buffer (read at end of step)
        if (t < 127) *(float4*)&el[(t + 1) & 1][err][ec4] = epf;

        // ---- h-dot: 3 gates x 4 batches over this thread's k-set (R4) ----
        float p[3][4];
#pragma unroll
        for (int b = 0; b < 4; ++b) {
            float4 ar = make_float4(0.f, 0.f, 0.f, 0.f), az = ar, an = ar;
#pragma unroll
            for (int i = 0; i < 8; ++i) {
                float4 h4 = *(const float4*)&hl[b][kc * 4 + i * 64];
                macc4(ar, wr[i], h4);
                macc4(az, wz[i], h4);
                macc4(an, wn[i], h4);
            }
            p[0][b] = hsum4(ar); p[1][b] = hsum4(az); p[2][b] = hsum4(an);
        }

        // reduce over kc within wave (kc = lane bits 4,5) — R4 verbatim
#pragma unroll
        for (int gg = 0; gg < 3; ++gg)
#pragma unroll
            for (int b = 0; b < 4; ++b) {
                float v = p[gg][b];
                v += __shfl_xor(v, 16);
                v += __shfl_xor(v, 32);
                p[gg][b] = v;
            }
        if ((tid & 48) == 0) {          // lane<16 of each wave
            const int w = tid >> 6;
#pragma unroll
            for (int gg = 0; gg < 3; ++gg)
#pragma unroll
                for (int b = 0; b < 4; ++b)
                    red[w][jl][gg * 4 + b] = p[gg][b];
        }
        __syncthreads();   // barrier 2

        // ---- finalize gates (64 threads) + publish — R4, x from LDS now --
        if (tid < 64) {
            float sr = bhr, sz = bhz, sn = bhn;
#pragma unroll
            for (int w = 0; w < 4; ++w) {
                sr += red[w][jf][0 + bf];
                sz += red[w][jf][4 + bf];
                sn += red[w][jf][8 + bf];
            }
            const float xr = xl[t & 1][0][bf * 16 + jf];   // b_ih pre-folded
            const float xz = xl[t & 1][1][bf * 16 + jf];
            const float xn = xl[t & 1][2][bf * 16 + jf];
            float r  = sigm(xr + sr);
            float z  = sigm(xz + sz);
            float n  = tanhf(xn + r * sn);
            float hn = (1.0f - z) * n + z * hprev;
            hprev = hn;
            if (t < 127) {
                union { float f; unsigned u; } cv; cv.f = hn;
                __hip_atomic_store(hx + (size_t)((t + 1) & 1) * 16384
                                      + (size_t)bg * 512 + jfg,
                                   ((unsigned long long)(unsigned)(t + 1) << 32) | cv.u,
                                   __ATOMIC_RELAXED, __HIP_MEMORY_SCOPE_AGENT);
            } else {
                h_out[(size_t)bg * 512 + jfg] = hn;
            }
        }

        // ---- x(t+1) by wave 0: AFTER publish, inside the LL-poll shadow ---
        if (t < 127 && tid < 64) {
            const int par = (t + 1) & 1;
            float4 a0 = make_float4(0,0,0,0), a1 = a0, a2 = a0;
#pragma unroll 8
            for (int i = 0; i < 64; ++i) {
                const float4 e = *(const float4*)&el[par][bf][i * 4];
                macc4(a0, *(const float4*)&Wx[jf][i * 4],       e);
                macc4(a1, *(const float4*)&Wx[16 + jf][i * 4],  e);
                macc4(a2, *(const float4*)&Wx[32 + jf][i * 4],  e);
            }
            xl[par][0][bf * 16 + jf] = hsum4(a0) + bxr;
            xl[par][1][bf * 16 + jf] = hsum4(a1) + bxz;
            xl[par][2][bf * 16 + jf] = hsum4(a2) + bxn;
        }
        // no bottom barrier: next staging writes hl (not el/xl parities in use)
    }
}

// ---------------------------------------------------------------------------
// K3: head (unchanged).
// ---------------------------------------------------------------------------
__global__ __launch_bounds__(256) void k_head(const float* __restrict__ h,
                                              const float* __restrict__ W3,
                                              const float* __restrict__ b3,
                                              float* __restrict__ out) {
    const int b = blockIdx.x;
    const int o = threadIdx.x;
    const float* hrow = h + (size_t)b * 512;
    float acc = b3[o];
#pragma unroll 8
    for (int k = 0; k < 512; ++k)
        acc += hrow[k] * W3[(size_t)k * 256 + o];
    out[(size_t)b * 256 + o] = acc;
}

// ---------------------------------------------------------------------------
extern "C" void kernel_launch(void* const* d_in, const int* in_sizes, int n_in,
                              void* d_out, int out_size, void* d_ws, size_t ws_size,
                              hipStream_t stream) {
    // 0:input 1:W1 2:b1 3:W2 4:b2 5:W_ih 6:W_hh 7:b_ih 8:b_hh 9:W3 10:b3
    const int*   tok  = (const int*)d_in[0];
    const float* W1   = (const float*)d_in[1];
    const float* b1   = (const float*)d_in[2];
    const float* W2   = (const float*)d_in[3];
    const float* b2   = (const float*)d_in[4];
    const float* W_ih = (const float*)d_in[5];
    const float* W_hh = (const float*)d_in[6];
    const float* b_ih = (const float*)d_in[7];
    const float* b_hh = (const float*)d_in[8];
    const float* W3   = (const float*)d_in[9];
    const float* b3   = (const float*)d_in[10];
    float* out = (float*)d_out;
    (void)ws_size;

    // workspace (floats) — xp is GONE (x-projection fused into the scan):
    //   emb : 1,048,576      (4096x256)
    //   hx  : 65,536 f-equiv (2x32x512 u64 LL slots; exact-tag poll makes
    //                         0xAA poison harmless — no memset needed)
    //   hfin: 16,384         (32x512)           total ~4.5 MB
    float* ws   = (float*)d_ws;
    float* emb  = ws;
    unsigned long long* hx = (unsigned long long*)(ws + 1048576);  // 8B-aligned
    float* hfin = ws + 1048576 + 131072;

    {   // fused embedding MLP
        dim3 grd(4096 / 64, 256 / 64);
        k_embed_gemm<<<grd, 256, 0, stream>>>(tok, W1, b1, W2, b2, emb);
    }
    // LL-exchange GRU scan with fused x-projection (k_xproj deleted)
    k_scan<<<256, 256, 0, stream>>>(emb, W_hh, W_ih, b_hh, b_ih, hx, hfin);

    // head on final hidden state
    k_head<<<32, 256, 0, stream>>>(hfin, W3, b3, out);
}

// Round 10
// 715.819 us; speedup vs baseline: 1.2858x; 1.2858x over previous
//
#include <hip/hip_runtime.h>
#include <cstddef>

#define THRESH 1e-6f
#define SPIN_LIMIT (1 << 20)

__device__ __forceinline__ float thrf(float x) { return x > THRESH ? x : 0.0f; }
__device__ __forceinline__ float sigm(float x) { return 1.0f / (1.0f + expf(-x)); }
__device__ __forceinline__ void macc4(float4& a, float4 w, float4 h) {
    a.x += w.x * h.x; a.y += w.y * h.y; a.z += w.z * h.z; a.w += w.w * h.w;
}
__device__ __forceinline__ float hsum4(float4 a) { return a.x + a.y + a.z + a.w; }

// ---------------------------------------------------------------------------
// K1: fused gather+MLP GEMM (unchanged — proven).
// ---------------------------------------------------------------------------
__global__ __launch_bounds__(256) void k_embed_gemm(const int* __restrict__ tok,
                                                    const float* __restrict__ W1,
                                                    const float* __restrict__ b1,
                                                    const float* __restrict__ W2,
                                                    const float* __restrict__ b2,
                                                    float* __restrict__ emb) {
    constexpr int BM = 64, BN = 64, BK = 32, K = 512, N = 256;
    __shared__ float As[BK][BM + 1];
    __shared__ float Bs[BK][BN];

    const int tid = threadIdx.x;
    const int bm = blockIdx.x * BM;
    const int bn = blockIdx.y * BN;
    const int tn = (tid & 15) * 4;
    const int tm = (tid >> 4) * 4;

    float acc[4][4] = {};

    for (int k0 = 0; k0 < K; k0 += BK) {
        for (int i = tid; i < BM * BK / 4; i += 256) {
            int c4 = (i & (BK / 4 - 1)) * 4;
            int r  = i / (BK / 4);
            int tv = tok[bm + r];
            float4 v  = *(const float4*)(W1 + (size_t)tv * K + k0 + c4);
            float4 bb = *(const float4*)(b1 + k0 + c4);
            As[c4 + 0][r] = thrf(v.x + bb.x);
            As[c4 + 1][r] = thrf(v.y + bb.y);
            As[c4 + 2][r] = thrf(v.z + bb.z);
            As[c4 + 3][r] = thrf(v.w + bb.w);
        }
        for (int i = tid; i < BK * BN / 4; i += 256) {
            int n4 = (i & 15) * 4;
            int kk = i >> 4;
            *(float4*)&Bs[kk][n4] = *(const float4*)(W2 + (size_t)(k0 + kk) * N + bn + n4);
        }
        __syncthreads();

        for (int k = 0; k < BK; ++k) {
            float a0 = As[k][tm + 0], a1 = As[k][tm + 1];
            float a2 = As[k][tm + 2], a3 = As[k][tm + 3];
            float b0 = Bs[k][tn + 0], b1v = Bs[k][tn + 1];
            float b2v = Bs[k][tn + 2], b3v = Bs[k][tn + 3];
            acc[0][0] += a0 * b0;  acc[0][1] += a0 * b1v;
            acc[0][2] += a0 * b2v; acc[0][3] += a0 * b3v;
            acc[1][0] += a1 * b0;  acc[1][1] += a1 * b1v;
            acc[1][2] += a1 * b2v; acc[1][3] += a1 * b3v;
            acc[2][0] += a2 * b0;  acc[2][1] += a2 * b1v;
            acc[2][2] += a2 * b2v; acc[2][3] += a2 * b3v;
            acc[3][0] += a3 * b0;  acc[3][1] += a3 * b1v;
            acc[3][2] += a3 * b2v; acc[3][3] += a3 * b3v;
        }
        __syncthreads();
    }

    const float4 bv = *(const float4*)(b2 + bn + tn);
    for (int i = 0; i < 4; ++i) {
        int m = bm + tm + i;
        float4 o;
        o.x = thrf(acc[i][0] + bv.x);
        o.y = thrf(acc[i][1] + bv.y);
        o.z = thrf(acc[i][2] + bv.z);
        o.w = thrf(acc[i][3] + bv.w);
        *(float4*)(emb + (size_t)m * N + bn + tn) = o;
    }
}

// ---------------------------------------------------------------------------
// K2: GRU scan — R4's proven structure VERBATIM on the critical path, with
// the x-projection fused at the STEP TOP, distributed over 192 threads,
// hidden inside the publish->visibility window of the LL exchange.
// (Resubmission of R9: the R9 bench died in the harness with a Trio nursery
// exception before any dispatch; kernel re-audited race-free — see journal.)
//
// 256 blocks x 256 threads = 8 groups (bid&7) x 32 members (bid>>3).
// Member owns j-slice [m*16,m*16+16); group owns batches [g*4,g*4+4).
// jl = tid&15 (j), kc = tid>>4 (strided k = kc*4 + i*64).  W_hh rows in
// VGPRs (96 f/thread — R4's mapping; R8 confirmed the fused kernel keeps
// it, VGPR 240).  LL flag-in-data exchange, red[]-reduce, 64-lane finalize:
// R4 verbatim.
//
// X-FUSION (R8 placement bug fixed):
//   - R8 ran the x-dot on wave 0 AFTER its publish -> wave 0 entered the
//     next poll ~1.3us late and barrier 1 inherited it every step (+2.3us).
//   - Now: at step t top, threads 0..191 each compute ONE gate output
//     x(t+1)[gg][jf][bf] = Wx[gg*16+jf]·el[par] + b_ih (64 macc4; Wx 4-way
//     broadcast, el 16-way broadcast; 3 waves in parallel ~0.3-0.5us) and
//     THEN join the LL poll.  Remote publish visibility is ~1-1.5us, so the
//     first poll load would return a stale tag in that window regardless:
//     the x-dot is free.  Wave 3 polls immediately.
//   - xl TRIPLE-buffered: writer at step t top -> slot (t+1)%3, finalize at
//     step t reads slot t%3 (written at t-1 top, ordered by barrier1(t));
//     the next overwrite of slot t%3 is at step t+2 top, which every writer
//     reaches only after the barrier2(t+1) rendezvous, which is after the
//     reader's finalize(t) read.  (Double-buffer would race here.)
//   - el double-buffered, prefetch distance 2: preamble stages rows t=0,1;
//     at step t top issue global load of rows t+2 (1 f4/thread), write to
//     el[t&1] after barrier 1 (read at t+1 top ordered by barrier2(t);
//     overwrite at t+2 ordered by the barrier1(t+2) rendezvous).
// ---------------------------------------------------------------------------
__global__ __launch_bounds__(256) void k_scan(const float* __restrict__ emb,   // (4096,256)
                                              const float* __restrict__ W_hh,  // (1536,512)
                                              const float* __restrict__ W_ih,  // (1536,256)
                                              const float* __restrict__ b_hh,  // (1536)
                                              const float* __restrict__ b_ih,  // (1536)
                                              unsigned long long* __restrict__ hx, // (2,32,512) u64
                                              float* __restrict__ h_out) {     // (32,512)
    constexpr int HS = 520;                        // pad: conflict-free h reads
    __shared__ __align__(16) float hl[4][HS];      //  8320 B  h staging
    __shared__ float red[4][16][12];               //  3072 B  cross-wave reduce
    __shared__ __align__(16) float Wx[48][260];    // 49920 B  W_ih rows
    __shared__ __align__(16) float el[2][4][260];  //  8320 B  emb row dbuf
    __shared__ float xl[3][3][64];                 //  2304 B  x results (mod-3)

    const int tid = threadIdx.x;
    const int g   = blockIdx.x & 7;
    const int m   = blockIdx.x >> 3;
    const int jl  = tid & 15;
    const int kc  = tid >> 4;                      // 0..15
    const int jglob = m * 16 + jl;

    // ---- W_hh rows -> registers (R4 verbatim; constant across 128 steps) --
    float4 wr[8], wz[8], wn[8];
#pragma unroll
    for (int i = 0; i < 8; ++i) {
        const int k = kc * 4 + i * 64;
        wr[i] = *(const float4*)(W_hh + (size_t)jglob * 512 + k);
        wz[i] = *(const float4*)(W_hh + (size_t)(512 + jglob) * 512 + k);
        wn[i] = *(const float4*)(W_hh + (size_t)(1024 + jglob) * 512 + k);
    }

    // ---- stage member's 48 W_ih rows -> LDS (once) ----
    for (int idx = tid; idx < 48 * 64; idx += 256) {
        const int rr = idx >> 6, c4 = (idx & 63) * 4;
        const int row = (rr >> 4) * 512 + m * 16 + (rr & 15);
        *(float4*)&Wx[rr][c4] = *(const float4*)(W_ih + (size_t)row * 256 + c4);
    }
    // ---- stage emb rows for t=0 (el[0]) and t=1 (el[1]) ----
    const int err = tid >> 6, ec4 = (tid & 63) * 4;
    *(float4*)&el[0][err][ec4] = *(const float4*)(emb + (size_t)(g * 4 + err) * 256 + ec4);
    *(float4*)&el[1][err][ec4] = *(const float4*)(emb + (size_t)(32 + g * 4 + err) * 256 + ec4);

    // x-dot worker persistent state (tid < 192): output (gg, jf2, bf2)
    const int gg  = tid >> 6;                      // 0..2 (gate) for tid<192
    const int jf2 = tid & 15;
    const int bf2 = (tid >> 4) & 3;
    float bx = 0.f;
    if (tid < 192) bx = b_ih[gg * 512 + m * 16 + jf2];

    // finalizer persistent state (tid < 64): (jf, bf) -> one h element
    const int jf  = tid & 15;
    const int bf  = (tid >> 4) & 3;
    const int jfg = m * 16 + jf;
    const int bg  = g * 4 + bf;
    float bhr = 0.f, bhz = 0.f, bhn = 0.f, hprev = 0.f;
    if (tid < 64) {
        bhr = b_hh[jfg];  bhz = b_hh[512 + jfg];  bhn = b_hh[1024 + jfg];
    }

    // h(0) = 0
    for (int i = tid; i < 4 * HS; i += 256) ((float*)hl)[i] = 0.f;
    __syncthreads();   // orders Wx / el[0..1] / hl staging

    // ---- x(0) -> xl slot 0 (read by finalize(0) after barrier2(0)) ----
    if (tid < 192) {
        float4 a = make_float4(0.f, 0.f, 0.f, 0.f);
#pragma unroll 8
        for (int i = 0; i < 64; ++i)
            macc4(a, *(const float4*)&Wx[gg * 16 + jf2][i * 4],
                     *(const float4*)&el[0][bf2][i * 4]);
        xl[0][gg][bf2 * 16 + jf2] = hsum4(a) + bx;
    }

    for (int t = 0; t < 128; ++t) {
        // emb prefetch for rows (t+2): issue global loads into regs now
        float4 epf = make_float4(0.f, 0.f, 0.f, 0.f);
        if (t < 126)
            epf = *(const float4*)(emb + (size_t)((t + 2) * 32 + g * 4 + err) * 256 + ec4);

        // ---- x(t+1) by threads 0..191: inside the publish-visibility
        //      window (remote tags are not yet visible anyway) ----
        if (t < 127 && tid < 192) {
            const int par = (t + 1) & 1;
            float4 a = make_float4(0.f, 0.f, 0.f, 0.f);
#pragma unroll 8
            for (int i = 0; i < 64; ++i)
                macc4(a, *(const float4*)&Wx[gg * 16 + jf2][i * 4],
                         *(const float4*)&el[par][bf2][i * 4]);
            xl[(t + 1) % 3][gg][bf2 * 16 + jf2] = hsum4(a) + bx;
        }

        // ---- LL receive of h(t) (t>0): R4 verbatim ----
        if (t > 0) {
            const unsigned tag = (unsigned)t;
            unsigned long long* base = hx + (size_t)(t & 1) * 16384 + (size_t)(g * 4) * 512;
            unsigned long long v[8];
#pragma unroll
            for (int p = 0; p < 8; ++p)
                v[p] = __hip_atomic_load(base + tid + 256 * p,
                                         __ATOMIC_RELAXED, __HIP_MEMORY_SCOPE_AGENT);
            int spins = 0;
            for (;;) {
                bool all = true;
#pragma unroll
                for (int p = 0; p < 8; ++p) {
                    if ((unsigned)(v[p] >> 32) != tag) {
                        all = false;
                        v[p] = __hip_atomic_load(base + tid + 256 * p,
                                                 __ATOMIC_RELAXED, __HIP_MEMORY_SCOPE_AGENT);
                    }
                }
                if (all || ++spins > SPIN_LIMIT) break;
                __builtin_amdgcn_s_sleep(1);
            }
#pragma unroll
            for (int p = 0; p < 8; ++p) {
                const int flat = tid + 256 * p;
                union { unsigned u; float f; } cv;
                cv.u = (unsigned)v[p];
                hl[flat >> 9][flat & 511] = cv.f;
            }
        }
        __syncthreads();   // barrier 1 (stage complete)

        // write emb prefetch (rows t+2) to el[t&1] == el[(t+2)&1]
        if (t < 126) *(float4*)&el[t & 1][err][ec4] = epf;

        // ---- h-dot: 3 gates x 4 batches over this thread's k-set (R4) ----
        float p[3][4];
#pragma unroll
        for (int b = 0; b < 4; ++b) {
            float4 ar = make_float4(0.f, 0.f, 0.f, 0.f), az = ar, an = ar;
#pragma unroll
            for (int i = 0; i < 8; ++i) {
                float4 h4 = *(const float4*)&hl[b][kc * 4 + i * 64];
                macc4(ar, wr[i], h4);
                macc4(az, wz[i], h4);
                macc4(an, wn[i], h4);
            }
            p[0][b] = hsum4(ar); p[1][b] = hsum4(az); p[2][b] = hsum4(an);
        }

        // reduce over kc within wave (kc = lane bits 4,5) — R4 verbatim
#pragma unroll
        for (int q = 0; q < 3; ++q)
#pragma unroll
            for (int b = 0; b < 4; ++b) {
                float v = p[q][b];
                v += __shfl_xor(v, 16);
                v += __shfl_xor(v, 32);
                p[q][b] = v;
            }
        if ((tid & 48) == 0) {          // lane<16 of each wave
            const int w = tid >> 6;
#pragma unroll
            for (int q = 0; q < 3; ++q)
#pragma unroll
                for (int b = 0; b < 4; ++b)
                    red[w][jl][q * 4 + b] = p[q][b];
        }
        __syncthreads();   // barrier 2

        // ---- finalize gates (64 threads) + publish — R4; x from xl LDS ----
        if (tid < 64) {
            float sr = bhr, sz = bhz, sn = bhn;
#pragma unroll
            for (int w = 0; w < 4; ++w) {
                sr += red[w][jf][0 + bf];
                sz += red[w][jf][4 + bf];
                sn += red[w][jf][8 + bf];
            }
            const int xs = t % 3;
            const float xr = xl[xs][0][bf * 16 + jf];   // b_ih pre-folded
            const float xz = xl[xs][1][bf * 16 + jf];
            const float xn = xl[xs][2][bf * 16 + jf];
            float r  = sigm(xr + sr);
            float z  = sigm(xz + sz);
            float n  = tanhf(xn + r * sn);
            float hn = (1.0f - z) * n + z * hprev;
            hprev = hn;
            if (t < 127) {
                union { float f; unsigned u; } cv; cv.f = hn;
                __hip_atomic_store(hx + (size_t)((t + 1) & 1) * 16384
                                      + (size_t)bg * 512 + jfg,
                                   ((unsigned long long)(unsigned)(t + 1) << 32) | cv.u,
                                   __ATOMIC_RELAXED, __HIP_MEMORY_SCOPE_AGENT);
            } else {
                h_out[(size_t)bg * 512 + jfg] = hn;
            }
        }
        // no bottom barrier: next step's x-dot reads el/xl slots whose
        // ordering is established by barrier 1/2 rendezvous (see header)
    }
}

// ---------------------------------------------------------------------------
// K3: head (unchanged).
// ---------------------------------------------------------------------------
__global__ __launch_bounds__(256) void k_head(const float* __restrict__ h,
                                              const float* __restrict__ W3,
                                              const float* __restrict__ b3,
                                              float* __restrict__ out) {
    const int b = blockIdx.x;
    const int o = threadIdx.x;
    const float* hrow = h + (size_t)b * 512;
    float acc = b3[o];
#pragma unroll 8
    for (int k = 0; k < 512; ++k)
        acc += hrow[k] * W3[(size_t)k * 256 + o];
    out[(size_t)b * 256 + o] = acc;
}

// ---------------------------------------------------------------------------
extern "C" void kernel_launch(void* const* d_in, const int* in_sizes, int n_in,
                              void* d_out, int out_size, void* d_ws, size_t ws_size,
                              hipStream_t stream) {
    // 0:input 1:W1 2:b1 3:W2 4:b2 5:W_ih 6:W_hh 7:b_ih 8:b_hh 9:W3 10:b3
    const int*   tok  = (const int*)d_in[0];
    const float* W1   = (const float*)d_in[1];
    const float* b1   = (const float*)d_in[2];
    const float* W2   = (const float*)d_in[3];
    const float* b2   = (const float*)d_in[4];
    const float* W_ih = (const float*)d_in[5];
    const float* W_hh = (const float*)d_in[6];
    const float* b_ih = (const float*)d_in[7];
    const float* b_hh = (const float*)d_in[8];
    const float* W3   = (const float*)d_in[9];
    const float* b3   = (const float*)d_in[10];
    float* out = (float*)d_out;
    (void)ws_size;

    // workspace (floats) — xp is GONE (x-projection fused into the scan):
    //   emb : 1,048,576      (4096x256)
    //   hx  : 65,536 f-equiv (2x32x512 u64 LL slots; exact-tag poll makes
    //                         0xAA poison harmless — no memset needed)
    //   hfin: 16,384         (32x512)           total ~4.5 MB
    float* ws   = (float*)d_ws;
    float* emb  = ws;
    unsigned long long* hx = (unsigned long long*)(ws + 1048576);  // 8B-aligned
    float* hfin = ws + 1048576 + 131072;

    {   // fused embedding MLP
        dim3 grd(4096 / 64, 256 / 64);
        k_embed_gemm<<<grd, 256, 0, stream>>>(tok, W1, b1, W2, b2, emb);
    }
    // LL-exchange GRU scan with step-top distributed x-fusion
    k_scan<<<256, 256, 0, stream>>>(emb, W_hh, W_ih, b_hh, b_ih, hx, hfin);

    // head on final hidden state
    k_head<<<32, 256, 0, stream>>>(hfin, W3, b3, out);
}